// Round 1
// baseline (758.211 us; speedup 1.0000x reference)
//
#include <hip/hip_runtime.h>
#include <hip/hip_bf16.h>
#include <stdint.h>

typedef __bf16 bf16_t;
typedef __bf16 bf16x8 __attribute__((ext_vector_type(8)));
typedef float f32x4 __attribute__((ext_vector_type(4)));

#define B_SZ   8192
#define D_IN   1024
#define D_HID  2048
#define D_OUT  1024

#define BM 128
#define BN 128
#define BK 64

// ---------------- multi-tensor f32 -> bf16 cast ----------------
struct CastJobs {
  const float* src[9];
  bf16_t* dst[9];
  int n8[9];
};

__global__ __launch_bounds__(256) void cast_kernel(CastJobs j) {
  const int which = blockIdx.y;
  const int t = blockIdx.x * 256 + threadIdx.x;
  if (t >= j.n8[which]) return;
  const float4* s = (const float4*)j.src[which];
  float4 a = s[2 * t], b = s[2 * t + 1];
  bf16x8 o;
  o[0] = (bf16_t)a.x; o[1] = (bf16_t)a.y; o[2] = (bf16_t)a.z; o[3] = (bf16_t)a.w;
  o[4] = (bf16_t)b.x; o[5] = (bf16_t)b.y; o[6] = (bf16_t)b.z; o[7] = (bf16_t)b.w;
  *(bf16x8*)(j.dst[which] + (size_t)t * 8) = o;
}

// ---------------- GEMM building blocks ----------------
// LDS tile: 128 rows x 64 cols bf16 (16 KiB), stored with st-style XOR swizzle:
// byte position p holds global data (row = p>>7, chunk = ((p>>4)&7) ^ (row&7)).
// global_load_lds writes linearly (wave base + lane*16), so we pre-swizzle the
// per-lane GLOBAL source address (rule 21: linear dest + inverse-swz source).
__device__ __forceinline__ void stage_tile(const bf16_t* __restrict__ src, int ld,
                                           int row_base, int col_base,
                                           char* tile, int wid, int lane) {
#pragma unroll
  for (int i = 0; i < 4; ++i) {
    int p = i * 4096 + wid * 1024 + lane * 16;
    int row = p >> 7;
    int chunk = ((p >> 4) & 7) ^ (row & 7);
    const bf16_t* g = src + (size_t)(row_base + row) * ld + col_base + chunk * 8;
    __builtin_amdgcn_global_load_lds(
        (const __attribute__((address_space(1))) void*)g,
        (__attribute__((address_space(3))) void*)(tile + i * 4096 + wid * 1024),
        16, 0, 0);
  }
}

// read one 8-wide bf16 fragment (16B) with matching XOR swizzle
__device__ __forceinline__ bf16x8 read_frag(const char* tile, int row, int k) {
  int slot = (k >> 3) ^ (row & 7);
  return *(const bf16x8*)(tile + row * 128 + slot * 16);
}

__device__ __forceinline__ float sigm(float x) { return 1.0f / (1.0f + __expf(-x)); }

// MODE 0: stacked gates GEMM. grid.y in [0,48): region = y>>4 (0:r, 1:z, 2:hx)
//   r/z: A = [x | hidden] (K=3072), B = [Wx* | Wh*]; hx: A = x (K=1024), B = Wxh
//   epilogue: rh = bf16(sigmoid(r)*hidden); zb = bf16(sigmoid(z)); hx = bf16(pre+b)
// MODE 1: Hh = rh @ Whh^T (K=2048). epilogue: hc = tanh(hx+acc);
//   nh = z*h + (1-z)*hc -> out_nh (f32) and nhb (bf16)
// MODE 2: out = nhb @ Who^T + b (K=2048, N=1024) -> out_y (f32)
template <int MODE>
__global__ __launch_bounds__(256, 2) void gru_gemm(
    const bf16_t* __restrict__ xb, const bf16_t* __restrict__ hb,
    const bf16_t* __restrict__ wxr, const bf16_t* __restrict__ whr,
    const bf16_t* __restrict__ wxz, const bf16_t* __restrict__ whz,
    const bf16_t* __restrict__ wxh, const bf16_t* __restrict__ whh,
    const bf16_t* __restrict__ who,
    const float* __restrict__ bxr, const float* __restrict__ bxz,
    const float* __restrict__ bxh, const float* __restrict__ bwo,
    const float* __restrict__ hidden_f32,
    bf16_t* __restrict__ rh, bf16_t* __restrict__ zb, bf16_t* __restrict__ hx,
    bf16_t* __restrict__ nhb, float* __restrict__ out_y, float* __restrict__ out_nh) {
  __shared__ char lds[32768];
  char* sA = lds;
  char* sB = lds + 16384;

  const int tid = threadIdx.x;
  const int wid = tid >> 6;
  const int lane = tid & 63;
  const int wr = wid >> 1, wc = wid & 1;
  const int l15 = lane & 15, lq = lane >> 4;

  const int bm = blockIdx.x * BM;
  int region = 0, bn;
  if (MODE == 0) { region = blockIdx.y >> 4; bn = (blockIdx.y & 15) * BN; }
  else bn = blockIdx.y * BN;

  int KT;
  const bf16_t *BX = nullptr, *BH = nullptr;
  if (MODE == 0) {
    if (region == 0)      { BX = wxr; BH = whr; KT = D_IN + D_HID; }
    else if (region == 1) { BX = wxz; BH = whz; KT = D_IN + D_HID; }
    else                  { BX = wxh;           KT = D_IN; }
  } else {
    KT = D_HID;
  }

  f32x4 acc[4][4];
#pragma unroll
  for (int i = 0; i < 4; ++i)
#pragma unroll
    for (int j = 0; j < 4; ++j) acc[i][j] = (f32x4){0.f, 0.f, 0.f, 0.f};

  for (int kt = 0; kt < KT; kt += BK) {
    const bf16_t *As, *Bs;
    int lda, ldb, ac, bc;
    if (MODE == 0) {
      if (kt < D_IN) { As = xb; lda = D_IN;  ac = kt;        Bs = BX; ldb = D_IN;  bc = kt; }
      else           { As = hb; lda = D_HID; ac = kt - D_IN; Bs = BH; ldb = D_HID; bc = kt - D_IN; }
    } else if (MODE == 1) { As = rh;  lda = D_HID; ac = kt; Bs = whh; ldb = D_HID; bc = kt; }
    else                  { As = nhb; lda = D_HID; ac = kt; Bs = who; ldb = D_HID; bc = kt; }

    stage_tile(As, lda, bm, ac, sA, wid, lane);
    stage_tile(Bs, ldb, bn, bc, sB, wid, lane);
    asm volatile("s_waitcnt vmcnt(0)" ::: "memory");
    __syncthreads();

#pragma unroll
    for (int kk = 0; kk < BK; kk += 32) {
      bf16x8 af[4], bfr[4];
      const int k = kk + lq * 8;
#pragma unroll
      for (int i = 0; i < 4; ++i) af[i]  = read_frag(sA, wr * 64 + i * 16 + l15, k);
#pragma unroll
      for (int i = 0; i < 4; ++i) bfr[i] = read_frag(sB, wc * 64 + i * 16 + l15, k);
#pragma unroll
      for (int mi = 0; mi < 4; ++mi)
#pragma unroll
        for (int ni = 0; ni < 4; ++ni)
          acc[mi][ni] = __builtin_amdgcn_mfma_f32_16x16x32_bf16(af[mi], bfr[ni], acc[mi][ni], 0, 0, 0);
    }
    __syncthreads();
  }

  // ---------------- fused epilogue ----------------
#pragma unroll
  for (int ni = 0; ni < 4; ++ni) {
    const int col = bn + wc * 64 + ni * 16 + l15;
#pragma unroll
    for (int mi = 0; mi < 4; ++mi) {
      const int row0 = bm + wr * 64 + mi * 16 + lq * 4;
#pragma unroll
      for (int j = 0; j < 4; ++j) {
        const int row = row0 + j;
        const float v = acc[mi][ni][j];
        if (MODE == 0) {
          const size_t off = (size_t)row * D_HID + col;
          if (region == 0) {
            float rr = sigm(v + bxr[col]);
            rh[off] = (bf16_t)(rr * hidden_f32[off]);
          } else if (region == 1) {
            zb[off] = (bf16_t)sigm(v + bxz[col]);
          } else {
            hx[off] = (bf16_t)(v + bxh[col]);
          }
        } else if (MODE == 1) {
          const size_t off = (size_t)row * D_HID + col;
          float hc = tanhf((float)hx[off] + v);
          float z = (float)zb[off];
          float h = hidden_f32[off];
          float nh = z * h + (1.0f - z) * hc;
          out_nh[off] = nh;
          nhb[off] = (bf16_t)nh;
        } else {
          out_y[(size_t)row * D_OUT + col] = v + bwo[col];
        }
      }
    }
  }
}

// ---------------- host launcher ----------------
extern "C" void kernel_launch(void* const* d_in, const int* in_sizes, int n_in,
                              void* d_out, int out_size, void* d_ws, size_t ws_size,
                              hipStream_t stream) {
  const float* x   = (const float*)d_in[0];
  const float* hid = (const float*)d_in[1];
  const float* Wxr = (const float*)d_in[2];
  const float* bxr = (const float*)d_in[3];
  const float* Whr = (const float*)d_in[4];
  const float* Wxz = (const float*)d_in[5];
  const float* bxz = (const float*)d_in[6];
  const float* Whz = (const float*)d_in[7];
  const float* Wxh = (const float*)d_in[8];
  const float* bxh = (const float*)d_in[9];
  const float* Whh = (const float*)d_in[10];
  const float* Who = (const float*)d_in[11];
  const float* bwo = (const float*)d_in[12];

  float* out_y  = (float*)d_out;                     // (8192,1024)
  float* out_nh = out_y + (size_t)B_SZ * D_OUT;      // (8192,2048)

  char* w = (char*)d_ws;
  auto alloc = [&](size_t bytes) { char* p = w; w += (bytes + 255) & ~(size_t)255; return p; };

  bf16_t* xb  = (bf16_t*)alloc((size_t)B_SZ * D_IN * 2);
  bf16_t* hb  = (bf16_t*)alloc((size_t)B_SZ * D_HID * 2);
  bf16_t* wxr = (bf16_t*)alloc((size_t)D_HID * D_IN * 2);
  bf16_t* whr = (bf16_t*)alloc((size_t)D_HID * D_HID * 2);
  bf16_t* wxz = (bf16_t*)alloc((size_t)D_HID * D_IN * 2);
  bf16_t* whz = (bf16_t*)alloc((size_t)D_HID * D_HID * 2);
  bf16_t* wxh = (bf16_t*)alloc((size_t)D_HID * D_IN * 2);
  bf16_t* whh = (bf16_t*)alloc((size_t)D_HID * D_HID * 2);
  bf16_t* who = (bf16_t*)alloc((size_t)D_OUT * D_HID * 2);
  bf16_t* rh  = (bf16_t*)alloc((size_t)B_SZ * D_HID * 2);
  bf16_t* zb  = (bf16_t*)alloc((size_t)B_SZ * D_HID * 2);
  bf16_t* hx  = (bf16_t*)alloc((size_t)B_SZ * D_HID * 2);
  bf16_t* nhb = (bf16_t*)alloc((size_t)B_SZ * D_HID * 2);

  CastJobs cj;
  const float* srcs[9] = {x, hid, Wxr, Whr, Wxz, Whz, Wxh, Whh, Who};
  bf16_t* dsts[9]      = {xb, hb, wxr, whr, wxz, whz, wxh, whh, who};
  const int ns[9] = {B_SZ * D_IN, B_SZ * D_HID,
                     D_HID * D_IN, D_HID * D_HID,
                     D_HID * D_IN, D_HID * D_HID,
                     D_HID * D_IN, D_HID * D_HID,
                     D_OUT * D_HID};
  for (int i = 0; i < 9; ++i) { cj.src[i] = srcs[i]; cj.dst[i] = dsts[i]; cj.n8[i] = ns[i] / 8; }

  // largest tensor: hidden = 16,777,216 elems -> n8 = 2,097,152 -> 8192 blocks
  cast_kernel<<<dim3(8192, 9), dim3(256), 0, stream>>>(cj);

  dim3 blk(256);
  gru_gemm<0><<<dim3(64, 48), blk, 0, stream>>>(xb, hb, wxr, whr, wxz, whz, wxh, whh, who,
                                                bxr, bxz, bxh, bwo, hid,
                                                rh, zb, hx, nhb, out_y, out_nh);
  gru_gemm<1><<<dim3(64, 16), blk, 0, stream>>>(xb, hb, wxr, whr, wxz, whz, wxh, whh, who,
                                                bxr, bxz, bxh, bwo, hid,
                                                rh, zb, hx, nhb, out_y, out_nh);
  gru_gemm<2><<<dim3(64, 8), blk, 0, stream>>>(xb, hb, wxr, whr, wxz, whz, wxh, whh, who,
                                               bxr, bxz, bxh, bwo, hid,
                                               rh, zb, hx, nhb, out_y, out_nh);
}